// Round 4
// baseline (1904.280 us; speedup 1.0000x reference)
//
#include <hip/hip_runtime.h>
#include <math.h>

#define EPS_C 0.001f
#define BATCH 16384
#define MAGIC 0x5EED1234
#define NB_PREP 64

__device__ __forceinline__ float wave_sum(float s) {
  #pragma unroll
  for (int off = 32; off > 0; off >>= 1) s += __shfl_xor(s, off);
  return s;
}

__device__ __forceinline__ void gridbar(int* bar, int nb, int gen) {
  __syncthreads();
  if (threadIdx.x == 0) {
    __threadfence();
    int a = __hip_atomic_fetch_add(&bar[0], 1, __ATOMIC_ACQ_REL, __HIP_MEMORY_SCOPE_AGENT);
    if (a == nb - 1) {
      __hip_atomic_store(&bar[0], 0, __ATOMIC_RELAXED, __HIP_MEMORY_SCOPE_AGENT);
      __hip_atomic_store(&bar[1], gen, __ATOMIC_RELEASE, __HIP_MEMORY_SCOPE_AGENT);
    } else {
      while (__hip_atomic_load(&bar[1], __ATOMIC_ACQUIRE, __HIP_MEMORY_SCOPE_AGENT) < gen) {}
    }
  }
  __syncthreads();
}

__global__ __launch_bounds__(256) void k_gram(const float* __restrict__ X, const float* __restrict__ C2,
                                              const float* __restrict__ Y, const float* __restrict__ x0,
                                              float* __restrict__ E0, float* __restrict__ E1,
                                              float* __restrict__ B1w, float* __restrict__ D11,
                                              float* __restrict__ Lam, float* __restrict__ C2t,
                                              float* __restrict__ Yt, float* __restrict__ xc,
                                              float* __restrict__ Fx) {
  const int job = blockIdx.x;
  const int t = threadIdx.x;
  if (job < 148) {
    int offA, offB, bi, bj, kind;
    if (job < 128) {
      int h = job >> 6, tile = job & 63;
      offA = offB = h ? 640 : 0; bi = (tile >> 3) * 64; bj = (tile & 7) * 64; kind = h;
    } else if (job < 144) {
      int tile = job - 128;
      offA = 640; offB = 512; bi = (tile >> 1) * 64; bj = (tile & 1) * 64; kind = 2;
    } else {
      int tile = job - 144;
      offA = 512; offB = 512; bi = (tile >> 1) * 64; bj = (tile & 1) * 64; kind = 3;
    }
    __shared__ float sA[32][65];
    __shared__ float sB[32][65];
    const int tj = t & 15, ti = t >> 4;
    float acc[4][4] = {};
    for (int k0 = 0; k0 < 1152; k0 += 32) {
      #pragma unroll
      for (int l = 0; l < 2; ++l) {
        int idx = t + l * 256;
        int kk = idx >> 4, c4 = (idx & 15) << 2;
        float4 va = *(const float4*)&X[(k0 + kk) * 1152 + offA + bi + c4];
        sA[kk][c4 + 0] = va.x; sA[kk][c4 + 1] = va.y; sA[kk][c4 + 2] = va.z; sA[kk][c4 + 3] = va.w;
        float4 vb = *(const float4*)&X[(k0 + kk) * 1152 + offB + bj + c4];
        sB[kk][c4 + 0] = vb.x; sB[kk][c4 + 1] = vb.y; sB[kk][c4 + 2] = vb.z; sB[kk][c4 + 3] = vb.w;
      }
      __syncthreads();
      #pragma unroll
      for (int kk = 0; kk < 32; ++kk) {
        float am[4], bn[4];
        #pragma unroll
        for (int q = 0; q < 4; ++q) am[q] = sA[kk][ti * 4 + q];
        #pragma unroll
        for (int q = 0; q < 4; ++q) bn[q] = sB[kk][tj * 4 + q];
        #pragma unroll
        for (int r = 0; r < 4; ++r)
          #pragma unroll
          for (int c = 0; c < 4; ++c)
            acc[r][c] = fmaf(am[r], bn[c], acc[r][c]);
      }
      __syncthreads();
    }
    if (kind <= 1) {
      float* E = kind ? E1 : E0;
      #pragma unroll
      for (int r = 0; r < 4; ++r) {
        float4 o = make_float4(acc[r][0], acc[r][1], acc[r][2], acc[r][3]);
        *(float4*)&E[(bi + ti * 4 + r) * 512 + bj + tj * 4] = o;
      }
    } else if (kind == 2) {
      #pragma unroll
      for (int r = 0; r < 4; ++r) {
        float4 o = make_float4(acc[r][0], acc[r][1], acc[r][2], acc[r][3]);
        *(float4*)&B1w[(bi + ti * 4 + r) * 128 + bj + tj * 4] = o;
      }
    } else {
      #pragma unroll
      for (int r = 0; r < 4; ++r)
        #pragma unroll
        for (int c = 0; c < 4; ++c) {
          int i = bi + ti * 4 + r, jj = bj + tj * 4 + c;
          float v = acc[r][c];
          D11[i * 128 + jj] = (jj < i) ? -v : 0.0f;
          if (i == jj) Lam[i] = 0.5f * (v + EPS_C);
        }
    }
  } else if (job == 148) {
    __shared__ float tt[32][33];
    const int a = t >> 5, b = t & 31;
    for (int tile = 0; tile < 64; ++tile) {
      int o0 = (tile & 3) * 32, r0 = (tile >> 2) * 32;
      __syncthreads();
      #pragma unroll
      for (int p = 0; p < 4; ++p) tt[a + p * 8][b] = C2[(o0 + a + p * 8) * 512 + r0 + b];
      __syncthreads();
      #pragma unroll
      for (int p = 0; p < 4; ++p) C2t[(r0 + a + p * 8) * 128 + o0 + b] = tt[b][a + p * 8];
    }
  } else if (job < 153) {
    __shared__ float tt[32][33];
    const int a = t >> 5, b = t & 31;
    int R0 = (job - 149) * 128;
    for (int tile = 0; tile < 64; ++tile) {
      int r0 = R0 + (tile & 3) * 32, c0 = (tile >> 2) * 32;
      __syncthreads();
      #pragma unroll
      for (int p = 0; p < 4; ++p) tt[a + p * 8][b] = Y[(c0 + a + p * 8) * 512 + r0 + b];
      __syncthreads();
      #pragma unroll
      for (int p = 0; p < 4; ++p) Yt[(r0 + a + p * 8) * 512 + c0 + b] = tt[b][a + p * 8];
    }
  } else {
    __shared__ float t1[1152];
    const int w = t >> 6, lane = t & 63;
    for (int k = w; k < 1152; k += 4) {
      float s = 0.f;
      #pragma unroll
      for (int m = 0; m < 8; ++m) s = fmaf(X[k * 1152 + m * 64 + lane], x0[m * 64 + lane], s);
      s = wave_sum(s);
      if (lane == 0) t1[k] = s;
    }
    __syncthreads();
    if (t < 128) {
      float s = 0.f;
      for (int k = 0; k < 1152; ++k) s = fmaf(X[k * 1152 + 512 + t], t1[k], s);
      xc[t] = -s;
    }
    for (int r = t; r < 512; r += 256) {
      float s = 0.f;
      for (int k = 0; k < 1152; ++k) s = fmaf(X[k * 1152 + 640 + r], t1[k], s);
      Fx[r] = s;
    }
  }
}

__device__ __forceinline__ void diag_factor(float* M, int kb) {
  const int lane = threadIdx.x;
  float* blk = M + kb * 64 * 640 + kb * 64;
  float col[64];
  #pragma unroll
  for (int r = 0; r < 64; ++r) col[r] = blk[r * 640 + lane];
  float invp = 1.0f;
  #pragma unroll
  for (int k = 0; k < 64; ++k) {
    float piv = __shfl(col[k], k);
    float inv = 1.0f / piv;
    if (lane == k) invp = inv;
    float m = col[k] * inv;
    bool act = lane > k;
    #pragma unroll
    for (int r = k + 1; r < 64; ++r) {
      float ckr = __shfl(col[r], k);
      if (act) col[r] -= ckr * m;
    }
  }
  #pragma unroll
  for (int r = 0; r < 64; ++r) {
    if (r > lane) col[r] *= invp;
    blk[r * 640 + lane] = col[r];
  }
}

__global__ __launch_bounds__(256) void k_prep(
    const float* __restrict__ E0, const float* __restrict__ E1,
    const float* __restrict__ Yt, const float* __restrict__ Y,
    const float* __restrict__ C2t, float* __restrict__ M, float* __restrict__ Gt,
    const float* __restrict__ B1w, const float* __restrict__ B2,
    const float* __restrict__ D21, const float* __restrict__ D22,
    const float* __restrict__ Fx, float* __restrict__ W1, float* __restrict__ W2,
    float* __restrict__ bias, int* __restrict__ bar) {
  const int bid = blockIdx.x;
  const int t = threadIdx.x;
  __shared__ float lds[8384];
  int g = 0;

  if (bid == 0 && t == 0) {
    __hip_atomic_store(&bar[0], 0, __ATOMIC_RELAXED, __HIP_MEMORY_SCOPE_AGENT);
    __hip_atomic_store(&bar[1], 0, __ATOMIC_RELAXED, __HIP_MEMORY_SCOPE_AGENT);
    __hip_atomic_store(&bar[2], MAGIC, __ATOMIC_RELEASE, __HIP_MEMORY_SCOPE_AGENT);
  }
  if (t == 0) {
    while (__hip_atomic_load(&bar[2], __ATOMIC_ACQUIRE, __HIP_MEMORY_SCOPE_AGENT) != MAGIC) {}
  }
  __syncthreads();

  #pragma unroll
  for (int rr = 0; rr < 8; ++rr) {
    int r = bid * 8 + rr;
    if (t < 128) {
      int c = t * 4;
      float4 e0 = *(const float4*)&E0[r * 512 + c];
      float4 e1 = *(const float4*)&E1[r * 512 + c];
      float4 yt = *(const float4*)&Yt[r * 512 + c];
      float4 yy = *(const float4*)&Y[r * 512 + c];
      float4 v;
      v.x = 0.5f * (e0.x + e1.x + yt.x - yy.x);
      v.y = 0.5f * (e0.y + e1.y + yt.y - yy.y);
      v.z = 0.5f * (e0.z + e1.z + yt.z - yy.z);
      v.w = 0.5f * (e0.w + e1.w + yt.w - yy.w);
      if (r >= c && r < c + 4) (&v.x)[r - c] += EPS_C;
      *(float4*)&M[r * 640 + c] = v;
    } else if (t < 160) {
      int c = (t - 128) * 4;
      *(float4*)&M[r * 640 + 512 + c] = *(const float4*)&C2t[r * 128 + c];
    }
  }
  gridbar(bar, NB_PREP, ++g);

  if (bid == 0 && t < 64) diag_factor(M, 0);
  gridbar(bar, NB_PREP, ++g);

  for (int kb = 0; kb < 8; ++kb) {
    {
      float* sD = lds;
      float* sDT = lds + 4160;
      float* sRD = lds + 8320;
      const int nUc = 576 - 64 * kb;
      const int nLr = 448 - 64 * kb;
      const int nBlk = (nUc + nLr) >> 6;
      if (bid < nBlk) {
        for (int l = t; l < 4096; l += 256) {
          int r = l >> 6, c = l & 63;
          float v = M[(kb * 64 + r) * 640 + kb * 64 + c];
          sD[r * 65 + c] = v;
          sDT[c * 65 + r] = v;
        }
        __syncthreads();
        if (t < 64) sRD[t] = 1.0f / sD[t * 65 + t];
        __syncthreads();
        if (t < 64) {
          int job = bid * 64 + t;
          if (job < nUc) {
            const int c = 64 * (kb + 1) + job;
            float v[64];
            #pragma unroll
            for (int i = 0; i < 64; ++i) v[i] = M[(kb * 64 + i) * 640 + c];
            #pragma unroll
            for (int i = 1; i < 64; ++i) {
              float a0 = v[i], a1 = 0.f;
              #pragma unroll
              for (int j = 0; j < i; j += 2) {
                a0 = fmaf(-sD[i * 65 + j], v[j], a0);
                if (j + 1 < i) a1 = fmaf(-sD[i * 65 + j + 1], v[j + 1], a1);
              }
              v[i] = a0 + a1;
            }
            #pragma unroll
            for (int i = 0; i < 64; ++i) M[(kb * 64 + i) * 640 + c] = v[i];
          } else {
            const int r = 64 * (kb + 1) + (job - nUc);
            float v[64];
            #pragma unroll
            for (int i = 0; i < 16; ++i) *(float4*)&v[i * 4] = *(const float4*)&M[r * 640 + kb * 64 + i * 4];
            #pragma unroll
            for (int j = 0; j < 64; ++j) {
              float a0 = v[j], a1 = 0.f;
              #pragma unroll
              for (int i = 0; i < j; i += 2) {
                a0 = fmaf(-v[i], sDT[j * 65 + i], a0);
                if (i + 1 < j) a1 = fmaf(-v[i + 1], sDT[j * 65 + i + 1], a1);
              }
              v[j] = (a0 + a1) * sRD[j];
            }
            #pragma unroll
            for (int i = 0; i < 16; ++i) *(float4*)&M[r * 640 + kb * 64 + i * 4] = *(float4*)&v[i * 4];
          }
        }
      }
    }
    gridbar(bar, NB_PREP, ++g);

    if (kb < 7) {
      const int ncol = 9 - kb, nrow = 7 - kb;
      const int ntile = ncol * nrow;
      float* sL = lds;
      float* sU2 = lds + 2080;
      if (bid < ntile) {
        const int ty = bid / ncol, tx = bid % ncol;
        const int base = 64 * (kb + 1);
        const int r0 = base + ty * 64, c0 = base + tx * 64;
        const int tj = t & 15, ti = t >> 4;
        float acc[4][4] = {};
        for (int k0 = 0; k0 < 64; k0 += 32) {
          #pragma unroll
          for (int l = 0; l < 2; ++l) {
            int idx = t + l * 256;
            int row = idx >> 3, k4 = (idx & 7) << 2;
            float4 v = *(const float4*)&M[(r0 + row) * 640 + kb * 64 + k0 + k4];
            sL[(k4 + 0) * 65 + row] = v.x; sL[(k4 + 1) * 65 + row] = v.y;
            sL[(k4 + 2) * 65 + row] = v.z; sL[(k4 + 3) * 65 + row] = v.w;
            int kk = idx >> 4, c4 = (idx & 15) << 2;
            float4 u4 = *(const float4*)&M[(kb * 64 + k0 + kk) * 640 + c0 + c4];
            sU2[kk * 65 + c4 + 0] = u4.x; sU2[kk * 65 + c4 + 1] = u4.y;
            sU2[kk * 65 + c4 + 2] = u4.z; sU2[kk * 65 + c4 + 3] = u4.w;
          }
          __syncthreads();
          #pragma unroll
          for (int kk = 0; kk < 32; ++kk) {
            float am[4], bn[4];
            #pragma unroll
            for (int q = 0; q < 4; ++q) am[q] = sL[kk * 65 + ti * 4 + q];
            #pragma unroll
            for (int q = 0; q < 4; ++q) bn[q] = sU2[kk * 65 + tj * 4 + q];
            #pragma unroll
            for (int r = 0; r < 4; ++r)
              #pragma unroll
              for (int c = 0; c < 4; ++c)
                acc[r][c] = fmaf(am[r], bn[c], acc[r][c]);
          }
          __syncthreads();
        }
        #pragma unroll
        for (int r = 0; r < 4; ++r) {
          float4 old = *(float4*)&M[(r0 + ti * 4 + r) * 640 + c0 + tj * 4];
          old.x -= acc[r][0]; old.y -= acc[r][1]; old.z -= acc[r][2]; old.w -= acc[r][3];
          *(float4*)&M[(r0 + ti * 4 + r) * 640 + c0 + tj * 4] = old;
        }
      }
      if (bid == 0) {
        __syncthreads();
        if (t < 64) diag_factor(M, kb + 1);
      }
      gridbar(bar, NB_PREP, ++g);
    }
  }

  for (int j = 7; j >= 0; --j) {
    {
      float* sU = lds;
      float* sRD2 = lds + 4160;
      if (bid < 32) {
        for (int l = t; l < 4096; l += 256) {
          int r = l >> 6, c = l & 63;
          sU[r * 65 + c] = M[(j * 64 + r) * 640 + j * 64 + c];
        }
        __syncthreads();
        if (t < 64) sRD2[t] = 1.0f / sU[t * 65 + t];
        __syncthreads();
        const int lane = t & 63;
        const int o = bid * 4 + (t >> 6);
        float v = M[(j * 64 + lane) * 640 + 512 + o];
        #pragma unroll
        for (int ii = 63; ii >= 0; --ii) {
          float s = (lane > ii) ? sU[ii * 65 + lane] * v : 0.f;
          s = wave_sum(s);
          if (lane == ii) v = (v - s) * sRD2[ii];
        }
        Gt[(j * 64 + lane) * 128 + o] = v;
      }
    }
    gridbar(bar, NB_PREP, ++g);
    if (j > 0) {
      const int ntile = 2 * j;
      float* sL = lds;
      float* sX = lds + 2080;
      if (bid < ntile) {
        const int rt = bid >> 1, ct = bid & 1;
        const int r0 = rt * 64, c0 = 512 + ct * 64;
        const int tj = t & 15, ti = t >> 4;
        float acc[4][4] = {};
        for (int k0 = 0; k0 < 64; k0 += 32) {
          #pragma unroll
          for (int l = 0; l < 2; ++l) {
            int idx = t + l * 256;
            int row = idx >> 3, k4 = (idx & 7) << 2;
            float4 v = *(const float4*)&M[(r0 + row) * 640 + j * 64 + k0 + k4];
            sL[(k4 + 0) * 65 + row] = v.x; sL[(k4 + 1) * 65 + row] = v.y;
            sL[(k4 + 2) * 65 + row] = v.z; sL[(k4 + 3) * 65 + row] = v.w;
            int kk = idx >> 4, c4 = (idx & 15) << 2;
            float4 x4 = *(const float4*)&Gt[(j * 64 + k0 + kk) * 128 + ct * 64 + c4];
            sX[kk * 65 + c4 + 0] = x4.x; sX[kk * 65 + c4 + 1] = x4.y;
            sX[kk * 65 + c4 + 2] = x4.z; sX[kk * 65 + c4 + 3] = x4.w;
          }
          __syncthreads();
          #pragma unroll
          for (int kk = 0; kk < 32; ++kk) {
            float am[4], bn[4];
            #pragma unroll
            for (int q = 0; q < 4; ++q) am[q] = sL[kk * 65 + ti * 4 + q];
            #pragma unroll
            for (int q = 0; q < 4; ++q) bn[q] = sX[kk * 65 + tj * 4 + q];
            #pragma unroll
            for (int r = 0; r < 4; ++r)
              #pragma unroll
              for (int c = 0; c < 4; ++c)
                acc[r][c] = fmaf(am[r], bn[c], acc[r][c]);
          }
          __syncthreads();
        }
        #pragma unroll
        for (int r = 0; r < 4; ++r) {
          float4 old = *(float4*)&M[(r0 + ti * 4 + r) * 640 + c0 + tj * 4];
          old.x -= acc[r][0]; old.y -= acc[r][1]; old.z -= acc[r][2]; old.w -= acc[r][3];
          *(float4*)&M[(r0 + ti * 4 + r) * 640 + c0 + tj * 4] = old;
        }
      }
      gridbar(bar, NB_PREP, ++g);
    }
  }

  if (bid < 8) {
    const int which = bid >> 2;
    const int o0 = ((bid >> 1) & 1) * 64, j0 = (bid & 1) * 64;
    const float* Bsrc = which ? B2 : B1w;
    const float* Dsrc = which ? D22 : D21;
    float* Wdst = which ? W2 : W1;
    float* sG = lds;
    float* sB = lds + 2080;
    const int tj = t & 15, ti = t >> 4;
    float acc[4][4] = {};
    for (int k0 = 0; k0 < 512; k0 += 32) {
      #pragma unroll
      for (int l = 0; l < 2; ++l) {
        int idx = t + l * 256;
        int kk = idx >> 4, c4 = (idx & 15) << 2;
        float4 g4 = *(const float4*)&Gt[(k0 + kk) * 128 + o0 + c4];
        sG[kk * 65 + c4 + 0] = g4.x; sG[kk * 65 + c4 + 1] = g4.y;
        sG[kk * 65 + c4 + 2] = g4.z; sG[kk * 65 + c4 + 3] = g4.w;
        float4 b4 = *(const float4*)&Bsrc[(k0 + kk) * 128 + j0 + c4];
        sB[kk * 65 + c4 + 0] = b4.x; sB[kk * 65 + c4 + 1] = b4.y;
        sB[kk * 65 + c4 + 2] = b4.z; sB[kk * 65 + c4 + 3] = b4.w;
      }
      __syncthreads();
      #pragma unroll
      for (int kk = 0; kk < 32; ++kk) {
        float mm[4], nn[4];
        #pragma unroll
        for (int q = 0; q < 4; ++q) mm[q] = sG[kk * 65 + ti * 4 + q];
        #pragma unroll
        for (int q = 0; q < 4; ++q) nn[q] = sB[kk * 65 + tj * 4 + q];
        #pragma unroll
        for (int r = 0; r < 4; ++r)
          #pragma unroll
          for (int c = 0; c < 4; ++c)
            acc[r][c] = fmaf(mm[r], nn[c], acc[r][c]);
      }
      __syncthreads();
    }
    #pragma unroll
    for (int r = 0; r < 4; ++r) {
      int o = o0 + ti * 4 + r;
      float4 d = *(const float4*)&Dsrc[o * 128 + j0 + tj * 4];
      float4 out = make_float4(acc[r][0] + d.x, acc[r][1] + d.y, acc[r][2] + d.z, acc[r][3] + d.w);
      *(float4*)&Wdst[o * 128 + j0 + tj * 4] = out;
    }
  } else if (bid == 8) {
    if (t < 128) {
      float s = 0.f;
      for (int a = 0; a < 512; ++a) s = fmaf(Gt[a * 128 + t], Fx[a], s);
      bias[t] = s;
    }
  }
}

__global__ __launch_bounds__(256) void k_ud(const float* __restrict__ u, const float* __restrict__ D12,
                                            const float* __restrict__ xc, float* __restrict__ baseT) {
  __shared__ float sU[32][65];
  __shared__ float sD[32][65];
  const int t = threadIdx.x;
  const int b0 = blockIdx.x * 64, i0 = blockIdx.y * 64;
  const int tm = t & 15, tn = t >> 4;
  float acc[4][4] = {};
  for (int k0 = 0; k0 < 128; k0 += 32) {
    #pragma unroll
    for (int l = 0; l < 2; ++l) {
      int idx = t + l * 256;
      int row = idx >> 3, k4 = (idx & 7) << 2;
      float4 v = *(const float4*)&u[(b0 + row) * 128 + k0 + k4];
      sU[k4 + 0][row] = v.x; sU[k4 + 1][row] = v.y; sU[k4 + 2][row] = v.z; sU[k4 + 3][row] = v.w;
      float4 d = *(const float4*)&D12[(i0 + row) * 128 + k0 + k4];
      sD[k4 + 0][row] = d.x; sD[k4 + 1][row] = d.y; sD[k4 + 2][row] = d.z; sD[k4 + 3][row] = d.w;
    }
    __syncthreads();
    #pragma unroll
    for (int kk = 0; kk < 32; ++kk) {
      float mm[4], nn[4];
      #pragma unroll
      for (int q = 0; q < 4; ++q) mm[q] = sU[kk][tm * 4 + q];
      #pragma unroll
      for (int q = 0; q < 4; ++q) nn[q] = sD[kk][tn * 4 + q];
      #pragma unroll
      for (int c = 0; c < 4; ++c)
        #pragma unroll
        for (int r = 0; r < 4; ++r)
          acc[c][r] = fmaf(nn[c], mm[r], acc[c][r]);
    }
    __syncthreads();
  }
  #pragma unroll
  for (int c = 0; c < 4; ++c) {
    int i = i0 + tn * 4 + c;
    float xcv = xc[i];
    float4 v = make_float4(acc[c][0] + xcv, acc[c][1] + xcv, acc[c][2] + xcv, acc[c][3] + xcv);
    *(float4*)&baseT[i * BATCH + b0 + tm * 4] = v;
  }
}

__global__ __launch_bounds__(256) void k_scan(const float* __restrict__ baseT, const float* __restrict__ D11g,
                                              const float* __restrict__ Lam, float* __restrict__ wT) {
  const int b = blockIdx.x * 256 + threadIdx.x;
  float w[128];
  #pragma unroll
  for (int i = 0; i < 128; ++i) {
    float acc0 = baseT[i * BATCH + b], acc1 = 0.f, acc2 = 0.f, acc3 = 0.f;
    const float* __restrict__ Drow = D11g + i * 128;
    #pragma unroll
    for (int j = 0; j + 4 <= i; j += 4) {
      acc0 = fmaf(w[j + 0], Drow[j + 0], acc0);
      acc1 = fmaf(w[j + 1], Drow[j + 1], acc1);
      acc2 = fmaf(w[j + 2], Drow[j + 2], acc2);
      acc3 = fmaf(w[j + 3], Drow[j + 3], acc3);
    }
    #pragma unroll
    for (int j = i & ~3; j < i; ++j) acc0 = fmaf(w[j], Drow[j], acc0);
    float zv = ((acc0 + acc1) + (acc2 + acc3)) / Lam[i];
    float az = fabsf(zv);
    float e = __expf(-2.0f * az);
    float th = (1.0f - e) / (1.0f + e);
    w[i] = copysignf(th, zv);
    wT[i * BATCH + b] = w[i];
  }
}

__global__ __launch_bounds__(256) void k_y(const float* __restrict__ wT, const float* __restrict__ u,
                                           const float* __restrict__ W1, const float* __restrict__ W2,
                                           const float* __restrict__ bias, float* __restrict__ y) {
  __shared__ float sA[32][65];
  __shared__ float sW[32][65];
  const int t = threadIdx.x;
  const int b0 = blockIdx.x * 64, o0 = blockIdx.y * 64;
  const int tn = t & 15, tm = t >> 4;
  float acc[4][4] = {};
  for (int k0 = 0; k0 < 128; k0 += 32) {
    #pragma unroll
    for (int l = 0; l < 2; ++l) {
      int idx = t + l * 256;
      int kk = idx >> 4, c4 = (idx & 15) << 2;
      float4 v = *(const float4*)&wT[(k0 + kk) * BATCH + b0 + c4];
      sA[kk][c4 + 0] = v.x; sA[kk][c4 + 1] = v.y; sA[kk][c4 + 2] = v.z; sA[kk][c4 + 3] = v.w;
      int row = idx >> 3, k4 = (idx & 7) << 2;
      float4 d = *(const float4*)&W1[(o0 + row) * 128 + k0 + k4];
      sW[k4 + 0][row] = d.x; sW[k4 + 1][row] = d.y; sW[k4 + 2][row] = d.z; sW[k4 + 3][row] = d.w;
    }
    __syncthreads();
    #pragma unroll
    for (int kk = 0; kk < 32; ++kk) {
      float mm[4], nn[4];
      #pragma unroll
      for (int q = 0; q < 4; ++q) mm[q] = sA[kk][tm * 4 + q];
      #pragma unroll
      for (int q = 0; q < 4; ++q) nn[q] = sW[kk][tn * 4 + q];
      #pragma unroll
      for (int r = 0; r < 4; ++r)
        #pragma unroll
        for (int c = 0; c < 4; ++c)
          acc[r][c] = fmaf(mm[r], nn[c], acc[r][c]);
    }
    __syncthreads();
  }
  for (int k0 = 0; k0 < 128; k0 += 32) {
    #pragma unroll
    for (int l = 0; l < 2; ++l) {
      int idx = t + l * 256;
      int row = idx >> 3, k4 = (idx & 7) << 2;
      float4 v = *(const float4*)&u[(b0 + row) * 128 + k0 + k4];
      sA[k4 + 0][row] = v.x; sA[k4 + 1][row] = v.y; sA[k4 + 2][row] = v.z; sA[k4 + 3][row] = v.w;
      float4 d = *(const float4*)&W2[(o0 + row) * 128 + k0 + k4];
      sW[k4 + 0][row] = d.x; sW[k4 + 1][row] = d.y; sW[k4 + 2][row] = d.z; sW[k4 + 3][row] = d.w;
    }
    __syncthreads();
    #pragma unroll
    for (int kk = 0; kk < 32; ++kk) {
      float mm[4], nn[4];
      #pragma unroll
      for (int q = 0; q < 4; ++q) mm[q] = sA[kk][tm * 4 + q];
      #pragma unroll
      for (int q = 0; q < 4; ++q) nn[q] = sW[kk][tn * 4 + q];
      #pragma unroll
      for (int r = 0; r < 4; ++r)
        #pragma unroll
        for (int c = 0; c < 4; ++c)
          acc[r][c] = fmaf(mm[r], nn[c], acc[r][c]);
    }
    __syncthreads();
  }
  #pragma unroll
  for (int r = 0; r < 4; ++r) {
    int bb = b0 + tm * 4 + r;
    float4 v = make_float4(acc[r][0] + bias[o0 + tn * 4 + 0],
                           acc[r][1] + bias[o0 + tn * 4 + 1],
                           acc[r][2] + bias[o0 + tn * 4 + 2],
                           acc[r][3] + bias[o0 + tn * 4 + 3]);
    *(float4*)&y[bb * 128 + o0 + tn * 4] = v;
  }
}

extern "C" void kernel_launch(void* const* d_in, const int* in_sizes, int n_in,
                              void* d_out, int out_size, void* d_ws, size_t ws_size,
                              hipStream_t stream) {
  const float* u   = (const float*)d_in[0];
  const float* X   = (const float*)d_in[1];
  const float* Y   = (const float*)d_in[2];
  const float* B2  = (const float*)d_in[3];
  const float* C2  = (const float*)d_in[4];
  const float* D21 = (const float*)d_in[5];
  const float* D22 = (const float*)d_in[6];
  const float* D12 = (const float*)d_in[7];
  const float* x0  = (const float*)d_in[8];

  float* ws = (float*)d_ws;
  float* E0    = ws;                   // 262144
  float* E1    = E0 + 262144;          // 262144
  float* M     = E1 + 262144;          // 327680
  float* Gt    = M + 327680;           // 65536
  float* B1w   = Gt + 65536;           // 65536
  float* W1    = B1w + 65536;          // 16384
  float* W2    = W1 + 16384;           // 16384
  float* D11   = W2 + 16384;           // 16384
  float* Lam   = D11 + 16384;          // 128
  float* xc    = Lam + 128;            // 128
  float* Fx    = xc + 128;             // 512
  float* bias  = Fx + 512;             // 128
  float* C2t   = bias + 128;           // 65536
  float* Yt    = C2t + 65536;          // 262144
  int*   bar   = (int*)(Yt + 262144);  // 64 ints
  float* baseT = Yt + 262144 + 64;     // 2097152
  float* wT    = baseT;                // in-place
  float* y     = (float*)d_out;

  k_gram<<<154, 256, 0, stream>>>(X, C2, Y, x0, E0, E1, B1w, D11, Lam, C2t, Yt, xc, Fx);
  k_prep<<<NB_PREP, 256, 0, stream>>>(E0, E1, Yt, Y, C2t, M, Gt, B1w, B2, D21, D22, Fx, W1, W2, bias, bar);
  k_ud<<<dim3(256, 2), 256, 0, stream>>>(u, D12, xc, baseT);
  k_scan<<<64, 256, 0, stream>>>(baseT, D11, Lam, wT);
  k_y<<<dim3(256, 2), 256, 0, stream>>>(wT, u, W1, W2, bias, y);
}

// Round 5
// 1260.510 us; speedup vs baseline: 1.5107x; 1.5107x over previous
//
#include <hip/hip_runtime.h>
#include <math.h>

#define EPS_C 0.001f
#define BATCH 16384

__device__ __forceinline__ float wave_sum(float s) {
  #pragma unroll
  for (int off = 32; off > 0; off >>= 1) s += __shfl_xor(s, off);
  return s;
}

// ============ k_gram: Gram tiles + transposes + xc/Fx, grid 173 ============
// jobs 0..63: E0 = X1^T X1; 64..127: E1 = X3^T X3; 128..143: B1 = X3^T X2;
// 144..147: H22 -> D11/Lam; 148..155: C2t; 156..171: Yt; 172: xc/Fx
__global__ __launch_bounds__(256) void k_gram(const float* __restrict__ X, const float* __restrict__ C2,
                                              const float* __restrict__ Y, const float* __restrict__ x0,
                                              float* __restrict__ E0, float* __restrict__ E1,
                                              float* __restrict__ B1w, float* __restrict__ D11,
                                              float* __restrict__ Lam, float* __restrict__ C2t,
                                              float* __restrict__ Yt, float* __restrict__ xc,
                                              float* __restrict__ Fx) {
  const int job = blockIdx.x;
  const int t = threadIdx.x;
  if (job < 148) {
    int offA, offB, bi, bj, kind;
    if (job < 128) {
      int h = job >> 6, tile = job & 63;
      offA = offB = h ? 640 : 0; bi = (tile >> 3) * 64; bj = (tile & 7) * 64; kind = h;
    } else if (job < 144) {
      int tile = job - 128;
      offA = 640; offB = 512; bi = (tile >> 1) * 64; bj = (tile & 1) * 64; kind = 2;
    } else {
      int tile = job - 144;
      offA = 512; offB = 512; bi = (tile >> 1) * 64; bj = (tile & 1) * 64; kind = 3;
    }
    __shared__ float sA[32][65];
    __shared__ float sB[32][65];
    const int tj = t & 15, ti = t >> 4;
    float acc[4][4] = {};
    for (int k0 = 0; k0 < 1152; k0 += 32) {
      #pragma unroll
      for (int l = 0; l < 2; ++l) {
        int idx = t + l * 256;
        int kk = idx >> 4, c4 = (idx & 15) << 2;
        float4 va = *(const float4*)&X[(k0 + kk) * 1152 + offA + bi + c4];
        sA[kk][c4 + 0] = va.x; sA[kk][c4 + 1] = va.y; sA[kk][c4 + 2] = va.z; sA[kk][c4 + 3] = va.w;
        float4 vb = *(const float4*)&X[(k0 + kk) * 1152 + offB + bj + c4];
        sB[kk][c4 + 0] = vb.x; sB[kk][c4 + 1] = vb.y; sB[kk][c4 + 2] = vb.z; sB[kk][c4 + 3] = vb.w;
      }
      __syncthreads();
      #pragma unroll
      for (int kk = 0; kk < 32; ++kk) {
        float am[4], bn[4];
        #pragma unroll
        for (int q = 0; q < 4; ++q) am[q] = sA[kk][ti * 4 + q];
        #pragma unroll
        for (int q = 0; q < 4; ++q) bn[q] = sB[kk][tj * 4 + q];
        #pragma unroll
        for (int r = 0; r < 4; ++r)
          #pragma unroll
          for (int c = 0; c < 4; ++c)
            acc[r][c] = fmaf(am[r], bn[c], acc[r][c]);
      }
      __syncthreads();
    }
    if (kind <= 1) {
      float* E = kind ? E1 : E0;
      #pragma unroll
      for (int r = 0; r < 4; ++r) {
        float4 o = make_float4(acc[r][0], acc[r][1], acc[r][2], acc[r][3]);
        *(float4*)&E[(bi + ti * 4 + r) * 512 + bj + tj * 4] = o;
      }
    } else if (kind == 2) {
      #pragma unroll
      for (int r = 0; r < 4; ++r) {
        float4 o = make_float4(acc[r][0], acc[r][1], acc[r][2], acc[r][3]);
        *(float4*)&B1w[(bi + ti * 4 + r) * 128 + bj + tj * 4] = o;
      }
    } else {
      #pragma unroll
      for (int r = 0; r < 4; ++r)
        #pragma unroll
        for (int c = 0; c < 4; ++c) {
          int i = bi + ti * 4 + r, jj = bj + tj * 4 + c;
          float v = acc[r][c];
          D11[i * 128 + jj] = (jj < i) ? -v : 0.0f;
          if (i == jj) Lam[i] = 0.5f * (v + EPS_C);
        }
    }
  } else if (job < 156) {
    __shared__ float tt[32][33];
    const int a = t >> 5, b = t & 31;
    const int j2 = job - 148;
    for (int l = 0; l < 8; ++l) {
      int tile = j2 * 8 + l;
      int o0 = (tile & 3) * 32, r0 = (tile >> 2) * 32;
      __syncthreads();
      #pragma unroll
      for (int p = 0; p < 4; ++p) tt[a + p * 8][b] = C2[(o0 + a + p * 8) * 512 + r0 + b];
      __syncthreads();
      #pragma unroll
      for (int p = 0; p < 4; ++p) C2t[(r0 + a + p * 8) * 128 + o0 + b] = tt[b][a + p * 8];
    }
  } else if (job < 172) {
    __shared__ float tt[32][33];
    const int a = t >> 5, b = t & 31;
    const int j3 = job - 156;
    for (int l = 0; l < 16; ++l) {
      int tile = j3 * 16 + l;
      int r0 = (tile & 15) * 32, c0 = (tile >> 4) * 32;
      __syncthreads();
      #pragma unroll
      for (int p = 0; p < 4; ++p) tt[a + p * 8][b] = Y[(c0 + a + p * 8) * 512 + r0 + b];
      __syncthreads();
      #pragma unroll
      for (int p = 0; p < 4; ++p) Yt[(r0 + a + p * 8) * 512 + c0 + b] = tt[b][a + p * 8];
    }
  } else {
    __shared__ float t1[1152];
    const int w = t >> 6, lane = t & 63;
    for (int k = w; k < 1152; k += 4) {
      float s = 0.f;
      #pragma unroll
      for (int m = 0; m < 8; ++m) s = fmaf(X[k * 1152 + m * 64 + lane], x0[m * 64 + lane], s);
      s = wave_sum(s);
      if (lane == 0) t1[k] = s;
    }
    __syncthreads();
    if (t < 128) {
      float s = 0.f;
      for (int k = 0; k < 1152; ++k) s = fmaf(X[k * 1152 + 512 + t], t1[k], s);
      xc[t] = -s;
    }
    for (int r = t; r < 512; r += 256) {
      float s = 0.f;
      for (int k = 0; k < 1152; ++k) s = fmaf(X[k * 1152 + 640 + r], t1[k], s);
      Fx[r] = s;
    }
  }
}

// ============ diag block LU factor (wave 0 only; also writes Ut cols + rdU) ============
__device__ __forceinline__ void diag_factor(float* __restrict__ M, float* __restrict__ Ut,
                                            float* __restrict__ rdU, int kb) {
  const int lane = threadIdx.x;
  float* blk = M + kb * 64 * 640 + kb * 64;
  float col[64];
  #pragma unroll
  for (int r = 0; r < 64; ++r) col[r] = blk[r * 640 + lane];
  float invp = 1.0f;
  #pragma unroll
  for (int k = 0; k < 64; ++k) {
    float piv = __shfl(col[k], k);
    float inv = 1.0f / piv;
    if (lane == k) invp = inv;
    float m = col[k] * inv;
    bool act = lane > k;
    #pragma unroll
    for (int r = k + 1; r < 64; ++r) {
      float ckr = __shfl(col[r], k);
      if (act) col[r] -= ckr * m;
    }
  }
  #pragma unroll
  for (int r = 0; r < 64; ++r) {
    if (r > lane) col[r] *= invp;
    blk[r * 640 + lane] = col[r];
  }
  rdU[kb * 64 + lane] = invp;
  const int c = kb * 64 + lane;
  #pragma unroll
  for (int r = 0; r < 64; ++r)
    if (r <= lane) Ut[c * 512 + kb * 64 + r] = col[r];
}

// ============ k_asm: assemble M=[E^T | C2^T]; block 0 also factors diag(0) ============
__global__ __launch_bounds__(256) void k_asm(const float* __restrict__ E0, const float* __restrict__ E1,
                                             const float* __restrict__ Yt, const float* __restrict__ Y,
                                             const float* __restrict__ C2t, float* __restrict__ M,
                                             float* __restrict__ Ut, float* __restrict__ rdU) {
  const int b = blockIdx.x, t = threadIdx.x;
  int r0, nr;
  if (b == 0) { r0 = 0; nr = 64; } else { r0 = 64 + (b - 1) * 8; nr = 8; }
  for (int rr = 0; rr < nr; ++rr) {
    int r = r0 + rr;
    if (t < 128) {
      int c = t * 4;
      float4 e0 = *(const float4*)&E0[r * 512 + c];
      float4 e1 = *(const float4*)&E1[r * 512 + c];
      float4 yt = *(const float4*)&Yt[r * 512 + c];
      float4 yy = *(const float4*)&Y[r * 512 + c];
      float4 v;
      v.x = 0.5f * (e0.x + e1.x + yt.x - yy.x);
      v.y = 0.5f * (e0.y + e1.y + yt.y - yy.y);
      v.z = 0.5f * (e0.z + e1.z + yt.z - yy.z);
      v.w = 0.5f * (e0.w + e1.w + yt.w - yy.w);
      if (r >= c && r < c + 4) (&v.x)[r - c] += EPS_C;
      *(float4*)&M[r * 640 + c] = v;
    } else if (t < 160) {
      int c = (t - 128) * 4;
      *(float4*)&M[r * 640 + 512 + c] = *(const float4*)&C2t[r * 128 + c];
    }
  }
  if (b == 0) {
    __syncthreads();
    if (t < 64) diag_factor(M, Ut, rdU, 0);
  }
}

// ============ k_panels: per-thread unrolled 64-deep triangular solves ============
__global__ __launch_bounds__(64) void k_panels(float* __restrict__ M, float* __restrict__ Ut, int kb) {
  __shared__ float sD[64 * 65];
  __shared__ float sDT[64 * 65];
  __shared__ float sRD[64];
  const int t = threadIdx.x;
  for (int l = 0; l < 64; ++l) {
    float v = M[(kb * 64 + l) * 640 + kb * 64 + t];
    sD[l * 65 + t] = v;
    sDT[t * 65 + l] = v;
  }
  __syncthreads();
  sRD[t] = 1.0f / sD[t * 65 + t];
  __syncthreads();
  const int nU = 9 - kb;
  const int b = blockIdx.x;
  if (b < nU) {
    const int c = 64 * (kb + 1) + b * 64 + t;
    float v[64];
    #pragma unroll
    for (int i = 0; i < 64; ++i) v[i] = M[(kb * 64 + i) * 640 + c];
    #pragma unroll
    for (int i = 1; i < 64; ++i) {
      float a0 = v[i], a1 = 0.f;
      #pragma unroll
      for (int j = 0; j < i; j += 2) {
        a0 = fmaf(-sD[i * 65 + j], v[j], a0);
        if (j + 1 < i) a1 = fmaf(-sD[i * 65 + j + 1], v[j + 1], a1);
      }
      v[i] = a0 + a1;
    }
    #pragma unroll
    for (int i = 0; i < 64; ++i) M[(kb * 64 + i) * 640 + c] = v[i];
    if (c < 512) {
      #pragma unroll
      for (int i = 0; i < 64; ++i) Ut[c * 512 + kb * 64 + i] = v[i];
    }
  } else {
    const int r = 64 * (kb + 1) + (b - nU) * 64 + t;
    float v[64];
    #pragma unroll
    for (int i = 0; i < 16; ++i) *(float4*)&v[i * 4] = *(const float4*)&M[r * 640 + kb * 64 + i * 4];
    #pragma unroll
    for (int j = 0; j < 64; ++j) {
      float a0 = v[j], a1 = 0.f;
      #pragma unroll
      for (int i = 0; i < j; i += 2) {
        a0 = fmaf(-v[i], sDT[j * 65 + i], a0);
        if (i + 1 < j) a1 = fmaf(-v[i + 1], sDT[j * 65 + i + 1], a1);
      }
      v[j] = (a0 + a1) * sRD[j];
    }
    #pragma unroll
    for (int i = 0; i < 16; ++i) *(float4*)&M[r * 640 + kb * 64 + i * 4] = *(float4*)&v[i * 4];
  }
}

// ============ k_trail: trailing update; tile (0,0) block also factors diag(kb+1) ============
__global__ __launch_bounds__(256) void k_trail(float* __restrict__ M, float* __restrict__ Ut,
                                               float* __restrict__ rdU, int kb) {
  __shared__ float sL[32][65];
  __shared__ float sU[32][65];
  const int t = threadIdx.x;
  const int base = 64 * (kb + 1);
  const int r0 = base + blockIdx.y * 64, c0 = base + blockIdx.x * 64;
  const int tj = t & 15, ti = t >> 4;
  float acc[4][4] = {};
  for (int k0 = 0; k0 < 64; k0 += 32) {
    #pragma unroll
    for (int l = 0; l < 2; ++l) {
      int idx = t + l * 256;
      int row = idx >> 3, k4 = (idx & 7) << 2;
      float4 v = *(const float4*)&M[(r0 + row) * 640 + kb * 64 + k0 + k4];
      sL[k4 + 0][row] = v.x; sL[k4 + 1][row] = v.y; sL[k4 + 2][row] = v.z; sL[k4 + 3][row] = v.w;
      int kk = idx >> 4, c4 = (idx & 15) << 2;
      float4 u4 = *(const float4*)&M[(kb * 64 + k0 + kk) * 640 + c0 + c4];
      sU[kk][c4 + 0] = u4.x; sU[kk][c4 + 1] = u4.y; sU[kk][c4 + 2] = u4.z; sU[kk][c4 + 3] = u4.w;
    }
    __syncthreads();
    #pragma unroll
    for (int kk = 0; kk < 32; ++kk) {
      float am[4], bn[4];
      #pragma unroll
      for (int q = 0; q < 4; ++q) am[q] = sL[kk][ti * 4 + q];
      #pragma unroll
      for (int q = 0; q < 4; ++q) bn[q] = sU[kk][tj * 4 + q];
      #pragma unroll
      for (int r = 0; r < 4; ++r)
        #pragma unroll
        for (int c = 0; c < 4; ++c)
          acc[r][c] = fmaf(am[r], bn[c], acc[r][c]);
    }
    __syncthreads();
  }
  #pragma unroll
  for (int r = 0; r < 4; ++r) {
    float4 old = *(float4*)&M[(r0 + ti * 4 + r) * 640 + c0 + tj * 4];
    old.x -= acc[r][0]; old.y -= acc[r][1]; old.z -= acc[r][2]; old.w -= acc[r][3];
    *(float4*)&M[(r0 + ti * 4 + r) * 640 + c0 + tj * 4] = old;
  }
  if (blockIdx.x == 0 && blockIdx.y == 0) {
    __syncthreads();
    if (t < 64) diag_factor(M, Ut, rdU, kb + 1);
  }
}

// ============ k_bs2: backsolve, one wave per RHS, column sweep, compile-time reg indexing ====
__global__ __launch_bounds__(256) void k_bs2(const float* __restrict__ M, const float* __restrict__ Ut,
                                             const float* __restrict__ rdU, float* __restrict__ Gt) {
  __shared__ float sRD[512];
  const int t = threadIdx.x;
  for (int l = t; l < 512; l += 256) sRD[l] = rdU[l];
  __syncthreads();
  const int lane = t & 63;
  const int o = (blockIdx.x * 256 + t) >> 6;  // 0..127
  float v[8];
  #pragma unroll
  for (int m = 0; m < 8; ++m) v[m] = M[(m * 64 + lane) * 640 + 512 + o];
  #pragma unroll
  for (int mi = 7; mi >= 0; --mi) {
    for (int li = 63; li >= 0; --li) {
      const int i = mi * 64 + li;
      float xi = __shfl(v[mi] * sRD[i], li);
      const float* Uc = Ut + i * 512;
      #pragma unroll
      for (int m = 0; m < mi; ++m) v[m] = fmaf(-Uc[m * 64 + lane], xi, v[m]);
      float um = Uc[mi * 64 + lane];
      float upd = fmaf(-um, xi, v[mi]);
      v[mi] = (lane == li) ? xi : ((lane < li) ? upd : v[mi]);
    }
  }
  #pragma unroll
  for (int m = 0; m < 8; ++m) Gt[(m * 64 + lane) * 128 + o] = v[m];
}

// ============ k_w: W1 = G@B1 + D21, W2 = G@B2 + D22, bias = G@Fx ============
__global__ __launch_bounds__(256) void k_w(const float* __restrict__ Gt, const float* __restrict__ B1w,
                                           const float* __restrict__ B2, const float* __restrict__ D21,
                                           const float* __restrict__ D22, const float* __restrict__ Fx,
                                           float* __restrict__ W1, float* __restrict__ W2,
                                           float* __restrict__ bias) {
  const int bid = blockIdx.x;
  const int t = threadIdx.x;
  if (bid < 8) {
    __shared__ float sG[32 * 65];
    __shared__ float sB[32 * 65];
    const int which = bid >> 2;
    const int o0 = ((bid >> 1) & 1) * 64, j0 = (bid & 1) * 64;
    const float* Bsrc = which ? B2 : B1w;
    const float* Dsrc = which ? D22 : D21;
    float* Wdst = which ? W2 : W1;
    const int tj = t & 15, ti = t >> 4;
    float acc[4][4] = {};
    for (int k0 = 0; k0 < 512; k0 += 32) {
      #pragma unroll
      for (int l = 0; l < 2; ++l) {
        int idx = t + l * 256;
        int kk = idx >> 4, c4 = (idx & 15) << 2;
        float4 g4 = *(const float4*)&Gt[(k0 + kk) * 128 + o0 + c4];
        sG[kk * 65 + c4 + 0] = g4.x; sG[kk * 65 + c4 + 1] = g4.y;
        sG[kk * 65 + c4 + 2] = g4.z; sG[kk * 65 + c4 + 3] = g4.w;
        float4 b4 = *(const float4*)&Bsrc[(k0 + kk) * 128 + j0 + c4];
        sB[kk * 65 + c4 + 0] = b4.x; sB[kk * 65 + c4 + 1] = b4.y;
        sB[kk * 65 + c4 + 2] = b4.z; sB[kk * 65 + c4 + 3] = b4.w;
      }
      __syncthreads();
      #pragma unroll
      for (int kk = 0; kk < 32; ++kk) {
        float mm[4], nn[4];
        #pragma unroll
        for (int q = 0; q < 4; ++q) mm[q] = sG[kk * 65 + ti * 4 + q];
        #pragma unroll
        for (int q = 0; q < 4; ++q) nn[q] = sB[kk * 65 + tj * 4 + q];
        #pragma unroll
        for (int r = 0; r < 4; ++r)
          #pragma unroll
          for (int c = 0; c < 4; ++c)
            acc[r][c] = fmaf(mm[r], nn[c], acc[r][c]);
      }
      __syncthreads();
    }
    #pragma unroll
    for (int r = 0; r < 4; ++r) {
      int o = o0 + ti * 4 + r;
      float4 d = *(const float4*)&Dsrc[o * 128 + j0 + tj * 4];
      float4 out = make_float4(acc[r][0] + d.x, acc[r][1] + d.y, acc[r][2] + d.z, acc[r][3] + d.w);
      *(float4*)&Wdst[o * 128 + j0 + tj * 4] = out;
    }
  } else {
    if (t < 128) {
      float s = 0.f;
      for (int a = 0; a < 512; ++a) s = fmaf(Gt[a * 128 + t], Fx[a], s);
      bias[t] = s;
    }
  }
}

// ============ k_batch: fused base-GEMM + scan + y-GEMM, 64 batch rows per block ============
__global__ __launch_bounds__(256) void k_batch(const float* __restrict__ u, const float* __restrict__ D12,
                                               const float* __restrict__ xc, const float* __restrict__ D11,
                                               const float* __restrict__ Lam, const float* __restrict__ W1,
                                               const float* __restrict__ W2, const float* __restrict__ bias,
                                               float* __restrict__ y) {
  __shared__ float sBW[128 * 64];   // base, then w in place: [i][b]
  __shared__ float sK[32 * 132];    // [k][128] staging (D12 / W1)
  __shared__ float sK2[32 * 132];   // [k][128] staging (W2)
  __shared__ float sU2[32 * 66];    // [k][64] staging (u)
  __shared__ float sRL[128];
  const int t = threadIdx.x;
  const int b0 = blockIdx.x * 64;
  if (t < 128) sRL[t] = 1.0f / Lam[t];
  const int ti = t >> 4, tj = t & 15;

  // ---- P1: base[i][b] = xc[i] + sum_k D12[i][k] * u[b][k] ----
  {
    float acc[8][4] = {};
    for (int k0 = 0; k0 < 128; k0 += 32) {
      #pragma unroll
      for (int l = 0; l < 4; ++l) {
        int idx = t + l * 256;
        int row = idx >> 3, k4 = (idx & 7) << 2;
        float4 d = *(const float4*)&D12[row * 128 + k0 + k4];
        sK[(k4 + 0) * 132 + row] = d.x; sK[(k4 + 1) * 132 + row] = d.y;
        sK[(k4 + 2) * 132 + row] = d.z; sK[(k4 + 3) * 132 + row] = d.w;
      }
      #pragma unroll
      for (int l = 0; l < 2; ++l) {
        int idx = t + l * 256;
        int row = idx >> 3, k4 = (idx & 7) << 2;
        float4 v = *(const float4*)&u[(b0 + row) * 128 + k0 + k4];
        sU2[(k4 + 0) * 66 + row] = v.x; sU2[(k4 + 1) * 66 + row] = v.y;
        sU2[(k4 + 2) * 66 + row] = v.z; sU2[(k4 + 3) * 66 + row] = v.w;
      }
      __syncthreads();
      #pragma unroll
      for (int kk = 0; kk < 32; ++kk) {
        float mi8[8], nb4[4];
        #pragma unroll
        for (int q = 0; q < 8; ++q) mi8[q] = sK[kk * 132 + ti * 8 + q];
        #pragma unroll
        for (int c = 0; c < 4; ++c) nb4[c] = sU2[kk * 66 + tj * 4 + c];
        #pragma unroll
        for (int q = 0; q < 8; ++q)
          #pragma unroll
          for (int c = 0; c < 4; ++c)
            acc[q][c] = fmaf(mi8[q], nb4[c], acc[q][c]);
      }
      __syncthreads();
    }
    #pragma unroll
    for (int q = 0; q < 8; ++q) {
      float xv = xc[ti * 8 + q];
      #pragma unroll
      for (int c = 0; c < 4; ++c) sBW[(ti * 8 + q) * 64 + tj * 4 + c] = acc[q][c] + xv;
    }
  }
  __syncthreads();

  // ---- P2: scan (one thread per batch row, w kept in registers, write w over base) ----
  if (t < 64) {
    float w[128];
    #pragma unroll
    for (int i = 0; i < 128; ++i) {
      float a0 = sBW[i * 64 + t], a1 = 0.f, a2 = 0.f, a3 = 0.f;
      const float* __restrict__ Drow = D11 + i * 128;
      #pragma unroll
      for (int j = 0; j + 4 <= i; j += 4) {
        a0 = fmaf(w[j + 0], Drow[j + 0], a0);
        a1 = fmaf(w[j + 1], Drow[j + 1], a1);
        a2 = fmaf(w[j + 2], Drow[j + 2], a2);
        a3 = fmaf(w[j + 3], Drow[j + 3], a3);
      }
      #pragma unroll
      for (int j = i & ~3; j < i; ++j) a0 = fmaf(w[j], Drow[j], a0);
      float zv = ((a0 + a1) + (a2 + a3)) * sRL[i];
      float az = fabsf(zv);
      float e = __expf(-2.0f * az);
      float th = (1.0f - e) / (1.0f + e);
      float wi = copysignf(th, zv);
      w[i] = wi;
      sBW[i * 64 + t] = wi;
    }
  }
  __syncthreads();

  // ---- P3: y[b][o] = sum_k w[k][b] W1[o][k] + sum_k u[b][k] W2[o][k] + bias[o] ----
  {
    float acc[4][8] = {};
    for (int k0 = 0; k0 < 128; k0 += 32) {
      #pragma unroll
      for (int l = 0; l < 4; ++l) {
        int idx = t + l * 256;
        int row = idx >> 3, k4 = (idx & 7) << 2;
        float4 d1 = *(const float4*)&W1[row * 128 + k0 + k4];
        sK[(k4 + 0) * 132 + row] = d1.x; sK[(k4 + 1) * 132 + row] = d1.y;
        sK[(k4 + 2) * 132 + row] = d1.z; sK[(k4 + 3) * 132 + row] = d1.w;
        float4 d2 = *(const float4*)&W2[row * 128 + k0 + k4];
        sK2[(k4 + 0) * 132 + row] = d2.x; sK2[(k4 + 1) * 132 + row] = d2.y;
        sK2[(k4 + 2) * 132 + row] = d2.z; sK2[(k4 + 3) * 132 + row] = d2.w;
      }
      #pragma unroll
      for (int l = 0; l < 2; ++l) {
        int idx = t + l * 256;
        int row = idx >> 3, k4 = (idx & 7) << 2;
        float4 v = *(const float4*)&u[(b0 + row) * 128 + k0 + k4];
        sU2[(k4 + 0) * 66 + row] = v.x; sU2[(k4 + 1) * 66 + row] = v.y;
        sU2[(k4 + 2) * 66 + row] = v.z; sU2[(k4 + 3) * 66 + row] = v.w;
      }
      __syncthreads();
      #pragma unroll
      for (int kk = 0; kk < 32; ++kk) {
        float wb[4], ub[4], wo[8], uo[8];
        #pragma unroll
        for (int q = 0; q < 4; ++q) {
          wb[q] = sBW[(k0 + kk) * 64 + ti * 4 + q];
          ub[q] = sU2[kk * 66 + ti * 4 + q];
        }
        #pragma unroll
        for (int c = 0; c < 8; ++c) {
          wo[c] = sK[kk * 132 + tj * 8 + c];
          uo[c] = sK2[kk * 132 + tj * 8 + c];
        }
        #pragma unroll
        for (int q = 0; q < 4; ++q)
          #pragma unroll
          for (int c = 0; c < 8; ++c)
            acc[q][c] = fmaf(wb[q], wo[c], fmaf(ub[q], uo[c], acc[q][c]));
      }
      __syncthreads();
    }
    float bo[8];
    #pragma unroll
    for (int c = 0; c < 8; ++c) bo[c] = bias[tj * 8 + c];
    #pragma unroll
    for (int q = 0; q < 4; ++q) {
      int bb = b0 + ti * 4 + q;
      float4 o1 = make_float4(acc[q][0] + bo[0], acc[q][1] + bo[1], acc[q][2] + bo[2], acc[q][3] + bo[3]);
      float4 o2 = make_float4(acc[q][4] + bo[4], acc[q][5] + bo[5], acc[q][6] + bo[6], acc[q][7] + bo[7]);
      *(float4*)&y[bb * 128 + tj * 8] = o1;
      *(float4*)&y[bb * 128 + tj * 8 + 4] = o2;
    }
  }
}

extern "C" void kernel_launch(void* const* d_in, const int* in_sizes, int n_in,
                              void* d_out, int out_size, void* d_ws, size_t ws_size,
                              hipStream_t stream) {
  const float* u   = (const float*)d_in[0];
  const float* X   = (const float*)d_in[1];
  const float* Y   = (const float*)d_in[2];
  const float* B2  = (const float*)d_in[3];
  const float* C2  = (const float*)d_in[4];
  const float* D21 = (const float*)d_in[5];
  const float* D22 = (const float*)d_in[6];
  const float* D12 = (const float*)d_in[7];
  const float* x0  = (const float*)d_in[8];

  float* ws = (float*)d_ws;
  float* E0    = ws;                   // 262144
  float* E1    = E0 + 262144;          // 262144
  float* M     = E1 + 262144;          // 327680
  float* Ut    = M + 327680;           // 262144
  float* Gt    = Ut + 262144;          // 65536
  float* B1w   = Gt + 65536;           // 65536
  float* C2t   = B1w + 65536;          // 65536
  float* Yt    = C2t + 65536;          // 262144
  float* W1    = Yt + 262144;          // 16384
  float* W2    = W1 + 16384;           // 16384
  float* D11   = W2 + 16384;           // 16384
  float* Lam   = D11 + 16384;          // 128
  float* rdU   = Lam + 128;            // 512
  float* xc    = rdU + 512;            // 128
  float* Fx    = xc + 128;             // 512
  float* bias  = Fx + 512;             // 128
  float* y     = (float*)d_out;

  k_gram<<<173, 256, 0, stream>>>(X, C2, Y, x0, E0, E1, B1w, D11, Lam, C2t, Yt, xc, Fx);
  k_asm<<<57, 256, 0, stream>>>(E0, E1, Yt, Y, C2t, M, Ut, rdU);

  for (int kb = 0; kb < 8; ++kb) {
    k_panels<<<16 - 2 * kb, 64, 0, stream>>>(M, Ut, kb);
    if (kb < 7)
      k_trail<<<dim3(9 - kb, 7 - kb), 256, 0, stream>>>(M, Ut, rdU, kb);
  }

  k_bs2<<<32, 256, 0, stream>>>(M, Ut, rdU, Gt);
  k_w<<<9, 256, 0, stream>>>(Gt, B1w, B2, D21, D22, Fx, W1, W2, bias);
  k_batch<<<256, 256, 0, stream>>>(u, D12, xc, D11, Lam, W1, W2, bias, y);
}